// Round 14
// baseline (55.658 us; speedup 1.0000x reference)
//
#include <hip/hip_runtime.h>

#define NB      32
#define NPB     16384
#define KTOP    2048
#define NF      64
#define NBINS   4096        // 12-bit bucket = key32 >> 20
#define NCH     8           // input chunks per batch (K1)
#define CROWS   2048        // rows per input chunk
#define NQ      16          // sort chunks per batch
#define CHSLOT  128         // candidate slots per sort chunk
#define SCAP    1024        // sort buffer capacity
#define STHR    256         // threads per sort block

// Padded LDS index for the bitonic net (u64 elements).
__device__ __forceinline__ int PAD(int i) { return i + (i >> 5); }

// Monotone map: float -> uint32 such that float order == unsigned order.
__device__ __forceinline__ unsigned mono(float f) {
  unsigned u = __float_as_uint(f);
  return (u & 0x80000000u) ? ~u : (u | 0x80000000u);
}

// K1: 256 blocks x 1024 thr (one block per 2048-row chunk): extract key
// column + private per-chunk u16 histogram (packed u32 stores).
__global__ __launch_bounds__(1024) void extract_hist_kernel(const float* __restrict__ in,
                                                            unsigned* __restrict__ keybuf,
                                                            unsigned* __restrict__ subhist32) {
  __shared__ unsigned h[NBINS];                  // 16 KiB
  const int g = blockIdx.x, tid = threadIdx.x;
  for (int i = tid; i < NBINS; i += 1024) h[i] = 0;
  __syncthreads();
  const int row0 = g * CROWS;
  unsigned k0 = mono(in[(size_t)(row0 + tid) * NF]);
  unsigned k1 = mono(in[(size_t)(row0 + tid + 1024) * NF]);
  keybuf[row0 + tid] = k0;
  keybuf[row0 + tid + 1024] = k1;
  atomicAdd(&h[k0 >> 20], 1u);
  atomicAdd(&h[k1 >> 20], 1u);
  __syncthreads();
  unsigned* out = subhist32 + (size_t)g * (NBINS / 2);
  for (int i = tid; i < NBINS / 2; i += 1024)
    out[i] = h[2 * i] | (h[2 * i + 1] << 16);    // counts <= 2048, fit u16
}

// K24: 512 blocks (16 per batch; block (b,q) owns candidate slots
// [E(128q), E(128q+128)), bin-aligned), 256 threads, ~2 blocks/CU so
// barriers/gather latency overlap across resident blocks. Each block:
// rebuild the batch scan from the 8 sub-hists (L2-hot), PULL its own
// candidates from keybuf into LDS, bitonic-sort (adaptive size), gather.
__global__ __launch_bounds__(STHR) void select_sort_gather_kernel(const float* __restrict__ in,
                                                                  const unsigned* __restrict__ keybuf,
                                                                  const unsigned short* __restrict__ subhist,
                                                                  float* __restrict__ out) {
  __shared__ unsigned ab_lds[NBINS];             // 16 KiB: slot counters
  __shared__ unsigned long long sb[SCAP + (SCAP >> 5)];   // 8.25 KiB padded
  __shared__ unsigned wtot[4], wsfx[4];
  __shared__ unsigned shE[2];
  __shared__ unsigned sh_D, sh_N;

  const int g = blockIdx.x, tid = threadIdx.x;
  const int b = g >> 4, q = g & 15;
  const int wid = tid >> 6, lane = tid & 63;
  const unsigned x1 = (unsigned)q * CHSLOT, x2 = x1 + CHSLOT;

  if (tid < 2) shE[tid] = 0xffffffffu;

  // ---- Batch scan: totals for my 16 bins [16*tid, 16*tid+16). ----
  unsigned tot[16];
#pragma unroll
  for (int j = 0; j < 16; ++j) tot[j] = 0;
#pragma unroll
  for (int c = 0; c < NCH; ++c) {
    const uint4* hp = (const uint4*)(subhist + (size_t)(b * NCH + c) * NBINS + 16 * tid);
    uint4 v0 = hp[0], v1 = hp[1];
    tot[0]  += v0.x & 0xffffu; tot[1]  += v0.x >> 16;
    tot[2]  += v0.y & 0xffffu; tot[3]  += v0.y >> 16;
    tot[4]  += v0.z & 0xffffu; tot[5]  += v0.z >> 16;
    tot[6]  += v0.w & 0xffffu; tot[7]  += v0.w >> 16;
    tot[8]  += v1.x & 0xffffu; tot[9]  += v1.x >> 16;
    tot[10] += v1.y & 0xffffu; tot[11] += v1.y >> 16;
    tot[12] += v1.z & 0xffffu; tot[13] += v1.z >> 16;
    tot[14] += v1.w & 0xffffu; tot[15] += v1.w >> 16;
  }
  unsigned s = 0;
#pragma unroll
  for (int j = 0; j < 16; ++j) s += tot[j];

  unsigned p = s;                                // inclusive suffix over lanes
  for (int off = 1; off < 64; off <<= 1) {
    unsigned t = __shfl_down(p, off);
    if (lane + off < 64) p += t;
  }
  if (lane == 0) wtot[wid] = p;
  __syncthreads();
  if (wid == 0) {
    unsigned own = (lane < 4) ? wtot[lane] : 0;
    unsigned p2 = own;
    for (int off = 1; off < 4; off <<= 1) {
      unsigned t = __shfl_down(p2, off);
      if (lane + off < 4) p2 += t;
    }
    if (lane < 4) wsfx[lane] = p2 - own;         // totals of waves above
  }
  __syncthreads();

  unsigned run = wsfx[wid] + (p - s);            // keys strictly above my bins
  unsigned ab[16];
#pragma unroll
  for (int j = 15; j >= 0; --j) {
    ab[j] = run;                                 // above[bin 16*tid+j]
    run += tot[j];
    if (ab[j] < KTOP && run >= KTOP) {           // exactly one bin satisfies
      sh_D = (unsigned)(16 * tid + j);
      sh_N = run;                                // total candidate count
    }
  }

  // ---- Chunk boundaries: E1 = min ab >= x1, E2 = min ab >= x2. ----
  unsigned m1 = 0xffffffffu, m2 = 0xffffffffu;
#pragma unroll
  for (int j = 0; j < 16; ++j) {
    if (ab[j] >= x1 && ab[j] < m1) m1 = ab[j];
    if (ab[j] >= x2 && ab[j] < m2) m2 = ab[j];
  }
  for (int off = 1; off < 64; off <<= 1) {
    unsigned t1 = __shfl_xor(m1, off), t2 = __shfl_xor(m2, off);
    m1 = m1 < t1 ? m1 : t1;
    m2 = m2 < t2 ? m2 : t2;
  }
  if (lane == 0) { atomicMin(&shE[0], m1); atomicMin(&shE[1], m2); }
  __syncthreads();

  const unsigned D = sh_D, N = sh_N;
  const unsigned E1 = shE[0];
  unsigned E2 = (x2 >= N) ? N : shE[1];
  if (E2 > N) E2 = N;
  if (E1 >= KTOP || E1 >= N) return;             // uniform exit: no output here
  unsigned len = E2 - E1;
  if (len == 0) return;
  if (len > SCAP) len = SCAP;                    // safety (degenerate data only)

  unsigned S = 128;
  while (S < len) S <<= 1;                       // sort size, <= SCAP

  // ---- Seed slot counters; zero only sb[len..S). ----
#pragma unroll
  for (int j = 0; j < 16; ++j) ab_lds[16 * tid + j] = ab[j] - E1;
  for (unsigned e = len + tid; e < S; e += STHR) sb[PAD(e)] = 0;
  __syncthreads();

  // ---- Pull candidates: scan the batch's 16K keys (L2-hot). ----
  const unsigned Dfl = D << 20;
  const uint4* kb4 = (const uint4*)(keybuf + (size_t)b * NPB);
  for (int i = tid; i < NPB / 4; i += STHR) {
    uint4 kv = kb4[i];
#pragma unroll
    for (int e = 0; e < 4; ++e) {
      unsigned k = (&kv.x)[e];
      if (k >= Dfl) {                            // bin >= D (candidate anywhere)
        unsigned bin = k >> 20;
        if (ab_lds[bin] < len) {                 // racy pre-check (monotonic-safe)
          unsigned slot = atomicAdd(&ab_lds[bin], 1u);
          if (slot < len) {
            unsigned li = (unsigned)(4 * i + e); // row within batch
            sb[PAD(slot)] = ((unsigned long long)k << 32) | (unsigned)~li;
          }
        }
      }
    }
  }
  __syncthreads();

  // ---- Bitonic sort, descending, adaptive size. ----
  for (unsigned size = 2; size <= S; size <<= 1) {
    for (unsigned stride = size >> 1; stride >= 1; stride >>= 1) {
      for (int t = tid; t < (int)(S / 2); t += STHR) {
        int pos = 2 * t - (t & (stride - 1));
        bool desc = ((pos & size) == 0);
        unsigned long long a = sb[PAD(pos)], bb = sb[PAD(pos + stride)];
        if (desc ? (a < bb) : (a > bb)) { sb[PAD(pos)] = bb; sb[PAD(pos + stride)] = a; }
      }
      __syncthreads();
    }
  }

  // ---- Gather output rows [E1, gend). ----
  const unsigned gend = (E2 < KTOP) ? E2 : KTOP;
  const int glen = (int)(gend - E1);
  const float4* inb = (const float4*)(in + (size_t)b * NPB * NF);
  float4* outb = (float4*)(out + ((size_t)b * KTOP + E1) * NF);
  for (int u = tid; u < glen * 16; u += STHR) {
    int r = u >> 4, f4 = u & 15;
    unsigned long long kv = sb[PAD(r)];
    int gi = (int)(~(unsigned)(kv & 0xffffffffu));
    outb[(size_t)r * 16 + f4] = inb[(size_t)gi * 16 + f4];
  }
}

extern "C" void kernel_launch(void* const* d_in, const int* in_sizes, int n_in,
                              void* d_out, int out_size, void* d_ws, size_t ws_size,
                              hipStream_t stream) {
  const float* in = (const float*)d_in[0];
  float* out = (float*)d_out;

  // d_ws layout: keybuf @0 (2 MiB), subhist u16 @2 MiB (2 MiB).
  unsigned* keybuf    = (unsigned*)d_ws;
  unsigned* subhist32 = (unsigned*)((char*)d_ws + (2u << 20));
  unsigned short* subhist16 = (unsigned short*)subhist32;

  extract_hist_kernel<<<NB * NCH, 1024, 0, stream>>>(in, keybuf, subhist32);
  select_sort_gather_kernel<<<NB * NQ, STHR, 0, stream>>>(in, keybuf, subhist16, out);
}

// Round 15
// 46.591 us; speedup vs baseline: 1.1946x; 1.1946x over previous
//
#include <hip/hip_runtime.h>

#define NB      32
#define NPB     16384
#define KTOP    2048
#define NF      64
#define NBINS   4096        // 12-bit bucket = key32 >> 20
#define NCH     8           // input chunks per batch (K1)
#define CROWS   2048        // rows per input chunk
#define NQ      8           // sort chunks per batch
#define CHSLOT  256         // candidate slots per sort chunk
#define SCAP    1024        // sort buffer capacity
#define STHR    512         // threads per sort block

// Padded LDS index for the bitonic net (u64 elements).
__device__ __forceinline__ int PAD(int i) { return i + (i >> 5); }

// Monotone map: float -> uint32 such that float order == unsigned order.
__device__ __forceinline__ unsigned mono(float f) {
  unsigned u = __float_as_uint(f);
  return (u & 0x80000000u) ? ~u : (u | 0x80000000u);
}

// K1: 256 blocks x 1024 thr (one block per 2048-row chunk): extract key
// column + private per-chunk u16 histogram (packed u32 stores).
__global__ __launch_bounds__(1024) void extract_hist_kernel(const float* __restrict__ in,
                                                            unsigned* __restrict__ keybuf,
                                                            unsigned* __restrict__ subhist32) {
  __shared__ unsigned h[NBINS];                  // 16 KiB
  const int g = blockIdx.x, tid = threadIdx.x;
  for (int i = tid; i < NBINS; i += 1024) h[i] = 0;
  __syncthreads();
  const int row0 = g * CROWS;
  unsigned k0 = mono(in[(size_t)(row0 + tid) * NF]);
  unsigned k1 = mono(in[(size_t)(row0 + tid + 1024) * NF]);
  keybuf[row0 + tid] = k0;
  keybuf[row0 + tid + 1024] = k1;
  atomicAdd(&h[k0 >> 20], 1u);
  atomicAdd(&h[k1 >> 20], 1u);
  __syncthreads();
  unsigned* out = subhist32 + (size_t)g * (NBINS / 2);
  for (int i = tid; i < NBINS / 2; i += 1024)
    out[i] = h[2 * i] | (h[2 * i + 1] << 16);    // counts <= 2048, fit u16
}

// K2s: 32 blocks x 256 thr (one per batch), 16 bins/thread. Computed ONCE:
// batch totals -> suffix scan -> aboveg16 (u16, 8 KB/batch) + finfo{D,N}.
__global__ __launch_bounds__(256) void scan_kernel(const unsigned short* __restrict__ subhist,
                                                   unsigned short* __restrict__ aboveg16,
                                                   uint2* __restrict__ finfo) {
  __shared__ unsigned wtot[4], wsfx[4];
  const int b = blockIdx.x, tid = threadIdx.x;
  const int wid = tid >> 6, lane = tid & 63;

  unsigned tot[16];
#pragma unroll
  for (int j = 0; j < 16; ++j) tot[j] = 0;
#pragma unroll
  for (int c = 0; c < NCH; ++c) {
    const uint4* hp = (const uint4*)(subhist + (size_t)(b * NCH + c) * NBINS + 16 * tid);
    uint4 v0 = hp[0], v1 = hp[1];
    tot[0]  += v0.x & 0xffffu; tot[1]  += v0.x >> 16;
    tot[2]  += v0.y & 0xffffu; tot[3]  += v0.y >> 16;
    tot[4]  += v0.z & 0xffffu; tot[5]  += v0.z >> 16;
    tot[6]  += v0.w & 0xffffu; tot[7]  += v0.w >> 16;
    tot[8]  += v1.x & 0xffffu; tot[9]  += v1.x >> 16;
    tot[10] += v1.y & 0xffffu; tot[11] += v1.y >> 16;
    tot[12] += v1.z & 0xffffu; tot[13] += v1.z >> 16;
    tot[14] += v1.w & 0xffffu; tot[15] += v1.w >> 16;
  }
  unsigned s = 0;
#pragma unroll
  for (int j = 0; j < 16; ++j) s += tot[j];

  unsigned p = s;                                // inclusive suffix over lanes
  for (int off = 1; off < 64; off <<= 1) {
    unsigned t = __shfl_down(p, off);
    if (lane + off < 64) p += t;
  }
  if (lane == 0) wtot[wid] = p;
  __syncthreads();
  if (wid == 0) {
    unsigned own = (lane < 4) ? wtot[lane] : 0;
    unsigned p2 = own;
    for (int off = 1; off < 4; off <<= 1) {
      unsigned t = __shfl_down(p2, off);
      if (lane + off < 4) p2 += t;
    }
    if (lane < 4) wsfx[lane] = p2 - own;         // totals of waves above
  }
  __syncthreads();

  unsigned run = wsfx[wid] + (p - s);            // keys strictly above my bins
  unsigned ab[16];
#pragma unroll
  for (int j = 15; j >= 0; --j) {
    ab[j] = run;                                 // above[bin 16*tid+j]
    run += tot[j];
    if (ab[j] < KTOP && run >= KTOP)             // exactly one bin satisfies
      finfo[b] = make_uint2((unsigned)(16 * tid + j), run);
  }
  uint4 o0, o1;                                  // pack ab (<= 16384) to u16
  o0.x = ab[0]  | (ab[1]  << 16); o0.y = ab[2]  | (ab[3]  << 16);
  o0.z = ab[4]  | (ab[5]  << 16); o0.w = ab[6]  | (ab[7]  << 16);
  o1.x = ab[8]  | (ab[9]  << 16); o1.y = ab[10] | (ab[11] << 16);
  o1.z = ab[12] | (ab[13] << 16); o1.w = ab[14] | (ab[15] << 16);
  uint4* ao = (uint4*)(aboveg16 + (size_t)b * NBINS + 16 * tid);
  ao[0] = o0; ao[1] = o1;
}

// K3: 256 blocks (8/batch; block (b,q) owns slots [E(256q), E(256q+256))),
// 512 thr. Read aboveg16 (8 KB) -> seed RAW-ab LDS counters + find E1/E2;
// pull candidates from keybuf (accept slot in [E1,E2)); bitonic-sort; gather.
__global__ __launch_bounds__(STHR) void pull_sort_gather_kernel(const float* __restrict__ in,
                                                                const unsigned* __restrict__ keybuf,
                                                                const unsigned short* __restrict__ aboveg16,
                                                                const uint2* __restrict__ finfo,
                                                                float* __restrict__ out) {
  __shared__ unsigned ab_lds[NBINS];             // 16 KiB: raw-ab slot counters
  __shared__ unsigned long long sb[SCAP + (SCAP >> 5)];   // 8.25 KiB padded
  __shared__ unsigned shE[2];

  const int g = blockIdx.x, tid = threadIdx.x;
  const int b = g >> 3, q = g & 7;
  const int lane = tid & 63;
  const unsigned x1 = (unsigned)q * CHSLOT, x2 = x1 + CHSLOT;

  const uint2 fi = finfo[b];
  const unsigned D = fi.x, N = fi.y;

  if (tid < 2) shE[tid] = 0xffffffffu;
  __syncthreads();

  // Load my 8 bins' ab values (u16), seed LDS counters, local min for E1/E2.
  const uint4 v = ((const uint4*)(aboveg16 + (size_t)b * NBINS))[tid];
  unsigned ab[8];
  ab[0] = v.x & 0xffffu; ab[1] = v.x >> 16;
  ab[2] = v.y & 0xffffu; ab[3] = v.y >> 16;
  ab[4] = v.z & 0xffffu; ab[5] = v.z >> 16;
  ab[6] = v.w & 0xffffu; ab[7] = v.w >> 16;
  unsigned m1 = 0xffffffffu, m2 = 0xffffffffu;
#pragma unroll
  for (int j = 0; j < 8; ++j) {
    ab_lds[8 * tid + j] = ab[j];
    if (ab[j] >= x1 && ab[j] < m1) m1 = ab[j];
    if (ab[j] >= x2 && ab[j] < m2) m2 = ab[j];
  }
  for (int off = 1; off < 64; off <<= 1) {
    unsigned t1 = __shfl_xor(m1, off), t2 = __shfl_xor(m2, off);
    m1 = m1 < t1 ? m1 : t1;
    m2 = m2 < t2 ? m2 : t2;
  }
  if (lane == 0) { atomicMin(&shE[0], m1); atomicMin(&shE[1], m2); }
  __syncthreads();

  const unsigned E1 = shE[0];
  unsigned E2 = (x2 >= N) ? N : shE[1];
  if (E2 > N) E2 = N;
  if (E1 >= KTOP || E1 >= N) return;             // uniform exit: no output here
  unsigned len = E2 - E1;
  if (len == 0) return;
  if (len > SCAP) len = SCAP;                    // safety (degenerate data only)

  unsigned S = 256;
  while (S < len) S <<= 1;                       // sort size, <= SCAP
  for (unsigned e = len + tid; e < S; e += STHR) sb[PAD(e)] = 0;

  // ---- Pull candidates: scan the batch's 16K keys (L2-hot). ----
  const unsigned Dfl = D << 20;
  const uint4* kb4 = (const uint4*)(keybuf + (size_t)b * NPB);
  for (int i = tid; i < NPB / 4; i += STHR) {
    uint4 kv = kb4[i];
#pragma unroll
    for (int e = 0; e < 4; ++e) {
      unsigned k = (&kv.x)[e];
      if (k >= Dfl) {                            // candidate (bin >= D)
        unsigned bin = k >> 20;
        if (ab_lds[bin] - E1 < len) {            // racy pre-check (monotonic-safe)
          unsigned slot = atomicAdd(&ab_lds[bin], 1u);
          if (slot - E1 < len) {                 // mine: slot in [E1, E2)
            unsigned li = (unsigned)(4 * i + e); // row within batch
            sb[PAD(slot - E1)] = ((unsigned long long)k << 32) | (unsigned)~li;
          }
        }
      }
    }
  }
  __syncthreads();

  // ---- Bitonic sort, descending, adaptive size. ----
  for (unsigned size = 2; size <= S; size <<= 1) {
    for (unsigned stride = size >> 1; stride >= 1; stride >>= 1) {
      for (int t = tid; t < (int)(S / 2); t += STHR) {
        int pos = 2 * t - (t & (stride - 1));
        bool desc = ((pos & size) == 0);
        unsigned long long a = sb[PAD(pos)], bb = sb[PAD(pos + stride)];
        if (desc ? (a < bb) : (a > bb)) { sb[PAD(pos)] = bb; sb[PAD(pos + stride)] = a; }
      }
      __syncthreads();
    }
  }

  // ---- Gather output rows [E1, gend). ----
  const unsigned gend = (E2 < KTOP) ? E2 : KTOP;
  const int glen = (int)(gend - E1);
  const float4* inb = (const float4*)(in + (size_t)b * NPB * NF);
  float4* outb = (float4*)(out + ((size_t)b * KTOP + E1) * NF);
  for (int u = tid; u < glen * 16; u += STHR) {
    int r = u >> 4, f4 = u & 15;
    unsigned long long kv = sb[PAD(r)];
    int gi = (int)(~(unsigned)(kv & 0xffffffffu));
    outb[(size_t)r * 16 + f4] = inb[(size_t)gi * 16 + f4];
  }
}

extern "C" void kernel_launch(void* const* d_in, const int* in_sizes, int n_in,
                              void* d_out, int out_size, void* d_ws, size_t ws_size,
                              hipStream_t stream) {
  const float* in = (const float*)d_in[0];
  float* out = (float*)d_out;

  // d_ws layout: keybuf @0 (2 MiB), subhist u16 @2 MiB (2 MiB),
  // aboveg16 @4 MiB (256 KiB), finfo @4.5 MiB.
  unsigned* keybuf    = (unsigned*)d_ws;
  unsigned* subhist32 = (unsigned*)((char*)d_ws + (2u << 20));
  unsigned short* subhist16 = (unsigned short*)subhist32;
  unsigned short* aboveg16  = (unsigned short*)((char*)d_ws + (4u << 20));
  uint2* finfo        = (uint2*)((char*)d_ws + (4u << 20) + (512u << 10));

  extract_hist_kernel<<<NB * NCH, 1024, 0, stream>>>(in, keybuf, subhist32);
  scan_kernel<<<NB, 256, 0, stream>>>(subhist16, aboveg16, finfo);
  pull_sort_gather_kernel<<<NB * NQ, STHR, 0, stream>>>(in, keybuf, aboveg16, finfo, out);
}